// Round 1
// baseline (498.657 us; speedup 1.0000x reference)
//
#include <hip/hip_runtime.h>
#include <math.h>

#define NB   16
#define HH   209
#define WW   133
#define CIN  64
#define COUT 128
#define OH   201
#define OW   129
#define NTAP 19
#define NW   (NTAP*CIN*COUT)
#define OT   3          // output rows per block; 201 = 3*67 exact
#define NTILE 67

#define XS 72   // bf16 elems per LDS row (64 + 8 pad; keeps 16B align, 2-way banks = free)

typedef __attribute__((ext_vector_type(8))) __bf16 bf16x8;
typedef __attribute__((ext_vector_type(4))) float f32x4;
typedef __attribute__((ext_vector_type(4))) unsigned short us4;

__device__ __forceinline__ unsigned short f2bf(float f) {
  unsigned int u = __builtin_bit_cast(unsigned int, f);
  u += 0x7FFFu + ((u >> 16) & 1u);       // RNE
  return (unsigned short)(u >> 16);
}

// sparse_weights [ci][co][k] fp32  ->  wt [k][co][ci] bf16
__global__ __launch_bounds__(256) void repack_w(const float* __restrict__ w,
                                                unsigned short* __restrict__ wt) {
  int gid = blockIdx.x * 256 + threadIdx.x;   // dst index, coalesced writes
  int ci = gid & 63;
  int co = (gid >> 6) & 127;
  int k  = gid >> 13;
  wt[gid] = f2bf(w[ci * (COUT * NTAP) + co * NTAP + k]);
}

// 3 output rows per block. x-row j (= oi0+j) is staged once at parity (par0+j)&1
// and consumed by output rows t with 0 <= j-t <= 8 (tap row r = j-t).
__global__ __launch_bounds__(256, 2) void conv_hex_mfma(const float* __restrict__ x,
                                                        const unsigned short* __restrict__ wt,
                                                        const float* __restrict__ offs,
                                                        float* __restrict__ out) {
  constexpr int c_start[9] = {0, 1, 3, 6, 8, 11, 13, 16, 18};
  constexpr int c_cnt[9]   = {1, 2, 3, 2, 3, 2, 3, 2, 1};
  constexpr int c_k[19]  = {18, 7,17, 6, 8,16, 1, 5, 0, 9,15, 2, 4, 3,10,14, 11,13, 12};
  constexpr int c_dw[19] = { 2, 3, 1, 2, 4, 0, 3, 1, 2, 4, 0, 3, 1, 2, 4, 0, 3, 1, 2};

  __shared__ unsigned short xs[2][82 * XS];   // one x-row per buffer, double buffered

  const int tid  = threadIdx.x;
  const int lane = tid & 63;
  const int wv   = tid >> 6;
  const int l15  = lane & 15;
  const int quad = lane >> 4;
  const int n0   = wv * 32;

  const int bid  = blockIdx.x;
  const int tile = bid % NTILE;
  const int b    = bid / NTILE;
  const int oi0  = tile * OT;
  const int par0 = oi0 & 1;

  // per-row valid limit + union column-fragment range
  int limt[OT];
  int f0u = 7, f1u = 0;
  #pragma unroll
  for (int t = 0; t < OT; ++t) {
    const int oi = oi0 + t;
    const int p  = (par0 + t) & 1;
    int ad = oi - 100; ad = ad < 0 ? -ad : ad;
    const int L = 128 - ad;                 // valid iff |oj-64| <= L
    limt[t] = L;
    const int na = 65 - p;
    int alr = 64 - L - p;
    int alo = alr <= 0 ? 0 : (alr + 1) >> 1;
    int ahi = (64 + L - p) >> 1;
    if (ahi > na - 1) ahi = na - 1;
    const int f0 = alo >> 4;
    const int f1 = ahi >> 4;
    f0u = f0 < f0u ? f0 : f0u;
    f1u = f1 > f1u ? f1 : f1u;
  }
  const int nfu    = f1u - f0u + 1;         // 1..5 (union over 3 rows)
  const int p0     = f0u * 16;
  const int npos   = nfu * 16;
  const int nchunk = (npos + 2) * 16;       // float4 chunks to stage per x-row

  // ---- zero-fill all 3 rows: opposite parity + same-parity outside union frags ----
  {
    const float4 z = make_float4(0.f, 0.f, 0.f, 0.f);
    for (int t = 0; t < OT; ++t) {
      float* outb = out + (size_t)((b * OH) + oi0 + t) * OW * COUT;
      const int p    = (par0 + t) & 1;
      const int opar = p ^ 1;
      const int nopp = 65 - opar;
      for (int idx = tid; idx < nopp * 32; idx += 256) {
        int q  = idx >> 5;
        int c4 = idx & 31;
        *(float4*)(outb + (size_t)(opar + 2 * q) * COUT + c4 * 4) = z;
      }
      const int na = 65 - p;
      const int hi_start = p0 + npos;
      const int hi_cnt   = na > hi_start ? na - hi_start : 0;
      const int tot      = (p0 + hi_cnt) * 32;
      for (int idx = tid; idx < tot; idx += 256) {
        int q  = idx >> 5;
        int a  = q < p0 ? q : hi_start + (q - p0);
        int c4 = idx & 31;
        *(float4*)(outb + (size_t)(p + 2 * a) * COUT + c4 * 4) = z;
      }
    }
  }

  f32x4 acc0[5][2], acc1[5][2], acc2[5][2];
  #pragma unroll
  for (int i = 0; i < 5; ++i)
    #pragma unroll
    for (int j = 0; j < 2; ++j) {
      acc0[i][j] = (f32x4){0.f, 0.f, 0.f, 0.f};
      acc1[i][j] = (f32x4){0.f, 0.f, 0.f, 0.f};
      acc2[i][j] = (f32x4){0.f, 0.f, 0.f, 0.f};
    }

  const float* xb = x + (size_t)b * (HH * WW * CIN);

  float4 stg[6];
  bf16x8 bfrag[3][2][2];   // prefetched B for the first-active row's taps

  auto load_stg = [&](int r) {
    const float* xr = xb + (size_t)(oi0 + r) * (WW * CIN);
    const int rpar = (par0 + r) & 1;
    #pragma unroll
    for (int i = 0; i < 6; ++i) {
      int c = tid + i * 256;
      if (c < nchunk) {
        int j  = c >> 4;
        int c4 = c & 15;
        int col = rpar + 2 * (p0 + j);
        if (col > WW - 1) col = WW - 1;    // clamp; results masked in epilogue
        stg[i] = *(const float4*)(xr + (size_t)col * CIN + c4 * 4);
      }
    }
  };
  auto store_stg = [&](int buf) {
    #pragma unroll
    for (int i = 0; i < 6; ++i) {
      int c = tid + i * 256;
      if (c < nchunk) {
        int j  = c >> 4;
        int c4 = c & 15;
        us4 o;
        o.x = f2bf(stg[i].x); o.y = f2bf(stg[i].y);
        o.z = f2bf(stg[i].z); o.w = f2bf(stg[i].w);
        *(us4*)(&xs[buf][j * XS + c4 * 4]) = o;
      }
    }
  };

  // compute one output row's taps for tap-row r from the staged buffer
  auto compute_row = [&](f32x4 (&accR)[5][2], int r, int pt,
                         const unsigned short* bufp, bool usePre) {
    const int st = c_start[r], cnt = c_cnt[r];
    #pragma unroll
    for (int t = 0; t < 3; ++t) {
      if (t < cnt) {
        bf16x8 b0[2], b1[2];               // [cout-half] for ks=0 / ks=1
        if (usePre) {
          b0[0] = bfrag[t][0][0]; b0[1] = bfrag[t][0][1];
          b1[0] = bfrag[t][1][0]; b1[1] = bfrag[t][1][1];
        } else {
          const unsigned short* wb = wt + (size_t)c_k[st + t] * (CIN * COUT);
          #pragma unroll
          for (int jj = 0; jj < 2; ++jj) {
            const unsigned short* wn = wb + (size_t)(n0 + jj * 16 + l15) * CIN + quad * 8;
            b0[jj] = *(const bf16x8*)(wn);
            b1[jj] = *(const bf16x8*)(wn + 32);
          }
        }
        const int s = (pt + c_dw[st + t]) >> 1;   // position shift of this tap
        #pragma unroll
        for (int mf = 0; mf < 5; ++mf) {
          if (mf < nfu) {
            const unsigned short* ap = &bufp[(mf * 16 + l15 + s) * XS + quad * 8];
            bf16x8 a0 = *(const bf16x8*)(ap);
            bf16x8 a1 = *(const bf16x8*)(ap + 32);
            accR[mf][0] = __builtin_amdgcn_mfma_f32_16x16x32_bf16(a0, b0[0], accR[mf][0], 0, 0, 0);
            accR[mf][1] = __builtin_amdgcn_mfma_f32_16x16x32_bf16(a0, b0[1], accR[mf][1], 0, 0, 0);
            accR[mf][0] = __builtin_amdgcn_mfma_f32_16x16x32_bf16(a1, b1[0], accR[mf][0], 0, 0, 0);
            accR[mf][1] = __builtin_amdgcn_mfma_f32_16x16x32_bf16(a1, b1[1], accR[mf][1], 0, 0, 0);
          }
        }
      }
    }
  };

  // prologue: stage x-row 0 into buf 0
  load_stg(0);
  store_stg(0);

  #pragma unroll 1
  for (int j = 0; j < OT + 8; ++j) {       // x-rows 0..10
    // prefetch B for row 0's taps BEFORE stg loads (waiting on B leaves stg in flight)
    if (j <= 8) {
      const int st = c_start[j], cnt = c_cnt[j];
      #pragma unroll
      for (int t = 0; t < 3; ++t) {
        if (t < cnt) {
          const unsigned short* wb = wt + (size_t)c_k[st + t] * (CIN * COUT);
          #pragma unroll
          for (int jj = 0; jj < 2; ++jj) {
            const unsigned short* wn = wb + (size_t)(n0 + jj * 16 + l15) * CIN + quad * 8;
            bfrag[t][0][jj] = *(const bf16x8*)(wn);
            bfrag[t][1][jj] = *(const bf16x8*)(wn + 32);
          }
        }
      }
    }
    if (j < OT + 7) load_stg(j + 1);       // next x-row globals, stay in flight
    __syncthreads();                       // buf j&1 ready for all waves
    const unsigned short* bufp = xs[j & 1];

    if (j <= 8)           compute_row(acc0, j,     par0,     bufp, true);
    if (j >= 1 && j <= 9) compute_row(acc1, j - 1, par0 ^ 1, bufp, false);
    if (j >= 2)           compute_row(acc2, j - 2, par0,     bufp, false);

    if (j < OT + 7) store_stg((j + 1) & 1);   // readers of that buf finished
                                              // before the barrier above
  }

  // ---- epilogue: elu(conv + offset), hex-masked; C/D: col=lane&15, row=quad*4+reg ----
  const float off0 = offs[n0 + l15];
  const float off1 = offs[n0 + 16 + l15];
  #pragma unroll
  for (int t = 0; t < OT; ++t) {
    f32x4 (&accR)[5][2] = (t == 0) ? acc0 : ((t == 1) ? acc1 : acc2);
    float* outb = out + (size_t)((b * OH) + oi0 + t) * OW * COUT;
    const int pt = (par0 + t) & 1;
    const int Lt = limt[t];
    #pragma unroll
    for (int mf = 0; mf < 5; ++mf) {
      if (mf < nfu) {
        #pragma unroll
        for (int rr = 0; rr < 4; ++rr) {
          int a  = (f0u + mf) * 16 + quad * 4 + rr;
          int oj = pt + 2 * a;
          if (oj <= OW - 1) {
            int adj = oj - 64; adj = adj < 0 ? -adj : adj;
            bool valid = adj <= Lt;
            float v0 = accR[mf][0][rr] + off0;
            float v1 = accR[mf][1][rr] + off1;
            float e0 = v0 > 0.f ? v0 : expm1f(v0);
            float e1 = v1 > 0.f ? v1 : expm1f(v1);
            outb[(size_t)oj * COUT + n0 + l15]      = valid ? e0 : 0.f;
            outb[(size_t)oj * COUT + n0 + 16 + l15] = valid ? e1 : 0.f;
          }
        }
      }
    }
  }
}

extern "C" void kernel_launch(void* const* d_in, const int* in_sizes, int n_in,
                              void* d_out, int out_size, void* d_ws, size_t ws_size,
                              hipStream_t stream) {
  const float* x   = (const float*)d_in[0];
  const float* sw  = (const float*)d_in[1];
  const float* off = (const float*)d_in[2];
  float* out = (float*)d_out;

  unsigned short* wtb = (unsigned short*)d_ws;     // 311 KB
  repack_w<<<NW / 256, 256, 0, stream>>>(sw, wtb);
  conv_hex_mfma<<<NB * NTILE, 256, 0, stream>>>(x, wtb, off, out);
}

// Round 2
// 398.753 us; speedup vs baseline: 1.2505x; 1.2505x over previous
//
#include <hip/hip_runtime.h>
#include <math.h>

#define NB   16
#define HH   209
#define WW   133
#define CIN  64
#define COUT 128
#define OH   201
#define OW   129
#define NTAP 19
#define NW   (NTAP*CIN*COUT)
#define NBLK (NB*OH)    // 3216 = 8 * 402: exact XCD-chunk split

#define XS 72   // bf16 elems per LDS row (64 + 8 pad; keeps 16B align, 2-way banks = free)

typedef __attribute__((ext_vector_type(8))) __bf16 bf16x8;
typedef __attribute__((ext_vector_type(4))) float f32x4;
typedef __attribute__((ext_vector_type(4))) unsigned short us4;

__device__ __forceinline__ unsigned short f2bf(float f) {
  unsigned int u = __builtin_bit_cast(unsigned int, f);
  u += 0x7FFFu + ((u >> 16) & 1u);       // RNE
  return (unsigned short)(u >> 16);
}

// sparse_weights [ci][co][k] fp32  ->  wt [k][co][ci] bf16
__global__ __launch_bounds__(256) void repack_w(const float* __restrict__ w,
                                                unsigned short* __restrict__ wt) {
  int gid = blockIdx.x * 256 + threadIdx.x;   // dst index, coalesced writes
  int ci = gid & 63;
  int co = (gid >> 6) & 127;
  int k  = gid >> 13;
  wt[gid] = f2bf(w[ci * (COUT * NTAP) + co * NTAP + k]);
}

// taps grouped by dh (row): within a dh all dw share parity -> one stride-2 window/row
__global__ __launch_bounds__(256) void conv_hex_mfma(const float* __restrict__ x,
                                                     const unsigned short* __restrict__ wt,
                                                     const float* __restrict__ offs,
                                                     float* __restrict__ out) {
  constexpr int c_start[9] = {0, 1, 3, 6, 8, 11, 13, 16, 18};
  constexpr int c_cnt[9]   = {1, 2, 3, 2, 3, 2, 3, 2, 1};
  constexpr int c_k[19]  = {18, 7,17, 6, 8,16, 1, 5, 0, 9,15, 2, 4, 3,10,14, 11,13, 12};
  constexpr int c_dw[19] = { 2, 3, 1, 2, 4, 0, 3, 1, 2, 4, 0, 3, 1, 2, 4, 0, 3, 1, 2};

  __shared__ unsigned short xs[2][82 * XS];   // 2 x 11.8 KB double buffer

  const int tid  = threadIdx.x;
  const int lane = tid & 63;
  const int wv   = tid >> 6;
  const int l15  = lane & 15;
  const int quad = lane >> 4;
  const int n0   = wv * 32;

  // XCD-aware swizzle: blockIdx round-robins across 8 XCDs, so give each XCD a
  // contiguous chunk of 402 logical blocks (= 2 whole batches, oi-contiguous).
  // Staging loads of x-rows then hit that XCD's L2 (~250cy) instead of HBM.
  const int bid0 = blockIdx.x;
  const int lb   = (bid0 & 7) * (NBLK / 8) + (bid0 >> 3);   // bijective: 3216 = 8*402
  const int oi  = lb % OH;
  const int b   = lb / OH;
  const int par = oi & 1;
  const int na  = 65 - par;                 // same-parity columns: a in [0, na)

  int ad = oi - 100; ad = ad < 0 ? -ad : ad;
  const int lim = 128 - ad;                 // valid iff |oj-64| <= lim

  int a_lo_raw = 64 - lim - par;
  int a_lo = a_lo_raw <= 0 ? 0 : (a_lo_raw + 1) >> 1;
  int a_hi = (64 + lim - par) >> 1;
  if (a_hi > na - 1) a_hi = na - 1;

  const int f0 = a_lo >> 4;
  const int f1 = a_hi >> 4;
  const int nf = f1 - f0 + 1;               // 1..5
  const int p0 = f0 * 16;
  const int npos   = nf * 16;
  const int nchunk = (npos + 2) * 16;       // float4 chunks to stage per x-row

  float* outb = out + (size_t)(b * OH + oi) * OW * COUT;

  f32x4 acc[5][2];
  #pragma unroll
  for (int i = 0; i < 5; ++i)
    #pragma unroll
    for (int j = 0; j < 2; ++j) acc[i][j] = (f32x4){0.f, 0.f, 0.f, 0.f};

  const float* xb = x + (size_t)b * (HH * WW * CIN);

  float4 stg[6];
  bf16x8 bfrag[3][2][2];

  auto load_stg = [&](int r) {
    const float* xr = xb + (size_t)(oi + r) * (WW * CIN);
    const int rpar = (par + r) & 1;
    #pragma unroll
    for (int i = 0; i < 6; ++i) {
      int c = tid + i * 256;
      if (c < nchunk) {
        int j  = c >> 4;
        int c4 = c & 15;
        int col = rpar + 2 * (p0 + j);
        if (col > WW - 1) col = WW - 1;    // clamp; results masked in epilogue
        stg[i] = *(const float4*)(xr + (size_t)col * CIN + c4 * 4);
      }
    }
  };
  auto store_stg = [&](int buf) {
    #pragma unroll
    for (int i = 0; i < 6; ++i) {
      int c = tid + i * 256;
      if (c < nchunk) {
        int j  = c >> 4;
        int c4 = c & 15;
        us4 o;   // native casts pair into v_cvt_pk_bf16_f32 (1 inst / 2 values)
        o.x = __builtin_bit_cast(unsigned short, (__bf16)stg[i].x);
        o.y = __builtin_bit_cast(unsigned short, (__bf16)stg[i].y);
        o.z = __builtin_bit_cast(unsigned short, (__bf16)stg[i].z);
        o.w = __builtin_bit_cast(unsigned short, (__bf16)stg[i].w);
        *(us4*)(&xs[buf][j * XS + c4 * 4]) = o;
      }
    }
  };

  // prologue: stage x-row 0 into buf 0 (no prior stores in vmcnt queue now)
  load_stg(0);
  store_stg(0);

  #pragma unroll
  for (int r = 0; r < 9; ++r) {
    // B fragments for this row's taps FIRST (so waiting on B leaves stg in flight)
    {
      const int st = c_start[r], cnt = c_cnt[r];
      #pragma unroll
      for (int t = 0; t < 3; ++t) {
        if (t < cnt) {
          const unsigned short* wb = wt + (size_t)c_k[st + t] * (CIN * COUT);
          #pragma unroll
          for (int j = 0; j < 2; ++j) {
            const unsigned short* wn = wb + (size_t)(n0 + j * 16 + l15) * CIN + quad * 8;
            bfrag[t][0][j] = *(const bf16x8*)(wn);
            bfrag[t][1][j] = *(const bf16x8*)(wn + 32);
          }
        }
      }
    }
    if (r < 8) load_stg(r + 1);            // x-globals for next row, stay in flight
    __syncthreads();                       // buf r&1 ready for all waves

    // compute taps of row r from buf r&1
    {
      const int st = c_start[r], cnt = c_cnt[r];
      const unsigned short* bufp = xs[r & 1];
      #pragma unroll
      for (int t = 0; t < 3; ++t) {
        if (t < cnt) {
          const int s = (par + c_dw[st + t]) >> 1;   // position shift of this tap
          #pragma unroll
          for (int ks = 0; ks < 2; ++ks) {
            #pragma unroll
            for (int mf = 0; mf < 5; ++mf) {
              if (mf < nf) {
                bf16x8 a = *(const bf16x8*)(&bufp[(mf * 16 + l15 + s) * XS + ks * 32 + quad * 8]);
                acc[mf][0] = __builtin_amdgcn_mfma_f32_16x16x32_bf16(a, bfrag[t][ks][0], acc[mf][0], 0, 0, 0);
                acc[mf][1] = __builtin_amdgcn_mfma_f32_16x16x32_bf16(a, bfrag[t][ks][1], acc[mf][1], 0, 0, 0);
              }
            }
          }
        }
      }
    }

    if (r < 8) store_stg((r + 1) & 1);     // readers of this buf finished before
                                           // the barrier above
  }

  // ---- zero-fill AFTER the loop: keeps block-start staging off the store-drain
  //      path; these stores overlap the epilogue VALU below ----
  {
    const float4 z = make_float4(0.f, 0.f, 0.f, 0.f);
    const int opar = par ^ 1;
    const int nopp = 65 - opar;
    for (int idx = tid; idx < nopp * 32; idx += 256) {
      int q  = idx >> 5;
      int c4 = idx & 31;
      *(float4*)(outb + (size_t)(opar + 2 * q) * COUT + c4 * 4) = z;
    }
    const int hi_start = p0 + npos;
    const int hi_cnt   = na > hi_start ? na - hi_start : 0;
    const int tot      = (p0 + hi_cnt) * 32;
    for (int idx = tid; idx < tot; idx += 256) {
      int q  = idx >> 5;
      int a  = q < p0 ? q : hi_start + (q - p0);
      int c4 = idx & 31;
      *(float4*)(outb + (size_t)(par + 2 * a) * COUT + c4 * 4) = z;
    }
  }

  // ---- epilogue: elu(conv + offset), hex-masked; C/D: col=lane&15, row=quad*4+reg ----
  const float off0 = offs[n0 + l15];
  const float off1 = offs[n0 + 16 + l15];
  #pragma unroll
  for (int mf = 0; mf < 5; ++mf) {
    if (mf < nf) {
      #pragma unroll
      for (int r = 0; r < 4; ++r) {
        int a  = (f0 + mf) * 16 + quad * 4 + r;
        int oj = par + 2 * a;
        if (oj <= OW - 1) {
          int adj = oj - 64; adj = adj < 0 ? -adj : adj;
          bool valid = adj <= lim;
          float v0 = acc[mf][0][r] + off0;
          float v1 = acc[mf][1][r] + off1;
          // elu: exp(v)-1 instead of expm1 — abs err ~1e-7, ~8x fewer VALU insts
          float e0 = v0 > 0.f ? v0 : (__expf(v0) - 1.0f);
          float e1 = v1 > 0.f ? v1 : (__expf(v1) - 1.0f);
          outb[(size_t)oj * COUT + n0 + l15]      = valid ? e0 : 0.f;
          outb[(size_t)oj * COUT + n0 + 16 + l15] = valid ? e1 : 0.f;
        }
      }
    }
  }
}

extern "C" void kernel_launch(void* const* d_in, const int* in_sizes, int n_in,
                              void* d_out, int out_size, void* d_ws, size_t ws_size,
                              hipStream_t stream) {
  const float* x   = (const float*)d_in[0];
  const float* sw  = (const float*)d_in[1];
  const float* off = (const float*)d_in[2];
  float* out = (float*)d_out;

  unsigned short* wtb = (unsigned short*)d_ws;     // 311 KB
  repack_w<<<NW / 256, 256, 0, stream>>>(sw, wtb);
  conv_hex_mfma<<<NBLK, 256, 0, stream>>>(x, wtb, off, out);
}

// Round 3
// 390.618 us; speedup vs baseline: 1.2766x; 1.0208x over previous
//
#include <hip/hip_runtime.h>
#include <math.h>

#define NB   16
#define HH   209
#define WW   133
#define CIN  64
#define COUT 128
#define OH   201
#define OW   129
#define NTAP 19
#define NW   (NTAP*CIN*COUT)
#define NBLK (NB*OH)    // 3216 = 8 * 402: exact XCD-chunk split

#define XS 72   // bf16 elems per LDS row (64 + 8 pad; keeps 16B align, 2-way banks = free)

typedef __attribute__((ext_vector_type(8))) __bf16 bf16x8;
typedef __attribute__((ext_vector_type(4))) float f32x4;
typedef __attribute__((ext_vector_type(4))) unsigned short us4;

__device__ __forceinline__ unsigned short f2bf(float f) {
  unsigned int u = __builtin_bit_cast(unsigned int, f);
  u += 0x7FFFu + ((u >> 16) & 1u);       // RNE
  return (unsigned short)(u >> 16);
}

// sparse_weights [ci][co][k] fp32  ->  wt [k][co][ci] bf16
__global__ __launch_bounds__(256) void repack_w(const float* __restrict__ w,
                                                unsigned short* __restrict__ wt) {
  int gid = blockIdx.x * 256 + threadIdx.x;   // dst index, coalesced writes
  int ci = gid & 63;
  int co = (gid >> 6) & 127;
  int k  = gid >> 13;
  wt[gid] = f2bf(w[ci * (COUT * NTAP) + co * NTAP + k]);
}

// taps grouped by dh (row): within a dh all dw share parity -> one stride-2 window/row
__global__ __launch_bounds__(256) void conv_hex_mfma(const float* __restrict__ x,
                                                     const unsigned short* __restrict__ wt,
                                                     const float* __restrict__ offs,
                                                     float* __restrict__ out) {
  constexpr int c_start[9] = {0, 1, 3, 6, 8, 11, 13, 16, 18};
  constexpr int c_cnt[9]   = {1, 2, 3, 2, 3, 2, 3, 2, 1};
  constexpr int c_k[19]  = {18, 7,17, 6, 8,16, 1, 5, 0, 9,15, 2, 4, 3,10,14, 11,13, 12};
  constexpr int c_dw[19] = { 2, 3, 1, 2, 4, 0, 3, 1, 2, 4, 0, 3, 1, 2, 4, 0, 3, 1, 2};

  __shared__ unsigned short xs[2][82 * XS];   // 2 x 11.8 KB double buffer

  const int tid  = threadIdx.x;
  const int lane = tid & 63;
  const int wv   = tid >> 6;
  const int l15  = lane & 15;
  const int quad = lane >> 4;
  const int n0   = wv * 32;

  // XCD-aware swizzle: each XCD gets a contiguous chunk of 402 logical blocks
  // (= 2 whole batches, oi-contiguous) -> x-row staging hits that XCD's L2.
  const int bid0 = blockIdx.x;
  const int lb   = (bid0 & 7) * (NBLK / 8) + (bid0 >> 3);   // bijective: 3216 = 8*402
  const int oi  = lb % OH;
  const int b   = lb / OH;
  const int par = oi & 1;
  const int na  = 65 - par;                 // same-parity columns: a in [0, na)

  int ad = oi - 100; ad = ad < 0 ? -ad : ad;
  const int lim = 128 - ad;                 // valid iff |oj-64| <= lim

  int a_lo_raw = 64 - lim - par;
  int a_lo = a_lo_raw <= 0 ? 0 : (a_lo_raw + 1) >> 1;
  int a_hi = (64 + lim - par) >> 1;
  if (a_hi > na - 1) a_hi = na - 1;

  const int f0 = a_lo >> 4;
  const int f1 = a_hi >> 4;
  const int nf = f1 - f0 + 1;               // 1..5
  const int p0 = f0 * 16;
  const int npos   = nf * 16;
  const int nchunk = (npos + 2) * 16;       // float4 chunks to stage per x-row

  float* outb = out + (size_t)(b * OH + oi) * OW * COUT;

  f32x4 acc[5][2];
  #pragma unroll
  for (int i = 0; i < 5; ++i)
    #pragma unroll
    for (int j = 0; j < 2; ++j) acc[i][j] = (f32x4){0.f, 0.f, 0.f, 0.f};

  const float* xb = x + (size_t)b * (HH * WW * CIN);

  float4 stg[6];
  bf16x8 bfrag[3][2][2];

  auto load_stg = [&](int r) {
    const float* xr = xb + (size_t)(oi + r) * (WW * CIN);
    const int rpar = (par + r) & 1;
    #pragma unroll
    for (int i = 0; i < 6; ++i) {
      int c = tid + i * 256;
      if (c < nchunk) {
        int j  = c >> 4;
        int c4 = c & 15;
        int col = rpar + 2 * (p0 + j);
        if (col > WW - 1) col = WW - 1;    // clamp; results masked in epilogue
        stg[i] = *(const float4*)(xr + (size_t)col * CIN + c4 * 4);
      }
    }
  };
  auto store_stg = [&](int buf) {
    #pragma unroll
    for (int i = 0; i < 6; ++i) {
      int c = tid + i * 256;
      if (c < nchunk) {
        int j  = c >> 4;
        int c4 = c & 15;
        us4 o;   // native casts pair into v_cvt_pk_bf16_f32 (1 inst / 2 values)
        o.x = __builtin_bit_cast(unsigned short, (__bf16)stg[i].x);
        o.y = __builtin_bit_cast(unsigned short, (__bf16)stg[i].y);
        o.z = __builtin_bit_cast(unsigned short, (__bf16)stg[i].z);
        o.w = __builtin_bit_cast(unsigned short, (__bf16)stg[i].w);
        *(us4*)(&xs[buf][j * XS + c4 * 4]) = o;
      }
    }
  };
  auto loadB = [&](int rr, int t) {         // B fragments for tap t of row rr
    const unsigned short* wb = wt + (size_t)c_k[c_start[rr] + t] * (CIN * COUT);
    #pragma unroll
    for (int j = 0; j < 2; ++j) {
      const unsigned short* wn = wb + (size_t)(n0 + j * 16 + l15) * CIN + quad * 8;
      bfrag[t][0][j] = *(const bf16x8*)(wn);
      bfrag[t][1][j] = *(const bf16x8*)(wn + 32);
    }
  };

  // prologue: B for row 0, stage x-row 0 into buf 0
  loadB(0, 0);                              // c_cnt[0] == 1
  load_stg(0);
  store_stg(0);
  __syncthreads();

  #pragma unroll
  for (int r = 0; r < 9; ++r) {
    // issue next-row staging loads AFTER the barrier: they fly under compute-r.
    // (issuing before __syncthreads is useless: the barrier's implicit
    //  s_waitcnt vmcnt(0) drains them on the spot — m97 lesson.)
    if (r < 8) load_stg(r + 1);

    // compute taps of row r from buf r&1; interleave B(r+1) prefetch into the
    // same bfrag slots right after tap t's last MFMA consumes them.
    {
      const int st = c_start[r], cnt = c_cnt[r];
      const unsigned short* bufp = xs[r & 1];
      #pragma unroll
      for (int t = 0; t < 3; ++t) {
        if (t < cnt) {
          const int s = (par + c_dw[st + t]) >> 1;   // position shift of this tap
          #pragma unroll
          for (int ks = 0; ks < 2; ++ks) {
            #pragma unroll
            for (int mf = 0; mf < 5; ++mf) {
              if (mf < nf) {
                bf16x8 a = *(const bf16x8*)(&bufp[(mf * 16 + l15 + s) * XS + ks * 32 + quad * 8]);
                acc[mf][0] = __builtin_amdgcn_mfma_f32_16x16x32_bf16(a, bfrag[t][ks][0], acc[mf][0], 0, 0, 0);
                acc[mf][1] = __builtin_amdgcn_mfma_f32_16x16x32_bf16(a, bfrag[t][ks][1], acc[mf][1], 0, 0, 0);
              }
            }
          }
          if (r < 8 && t < c_cnt[r + 1]) loadB(r + 1, t);   // prefetch next row's tap t
        }
      }
      if (r < 8) {                          // taps next row has but this row didn't
        #pragma unroll
        for (int t = 0; t < 3; ++t)
          if (t >= cnt && t < c_cnt[r + 1]) loadB(r + 1, t);
      }
    }

    if (r < 8) {
      store_stg((r + 1) & 1);   // vm-wait lands here, after ~600cy of compute
      __syncthreads();          // drains only ~settled B-prefetches
    }
  }

  // ---- zero-fill AFTER the loop: off the staging critical path; these stores
  //      overlap the epilogue VALU below ----
  {
    const float4 z = make_float4(0.f, 0.f, 0.f, 0.f);
    const int opar = par ^ 1;
    const int nopp = 65 - opar;
    for (int idx = tid; idx < nopp * 32; idx += 256) {
      int q  = idx >> 5;
      int c4 = idx & 31;
      *(float4*)(outb + (size_t)(opar + 2 * q) * COUT + c4 * 4) = z;
    }
    const int hi_start = p0 + npos;
    const int hi_cnt   = na > hi_start ? na - hi_start : 0;
    const int tot      = (p0 + hi_cnt) * 32;
    for (int idx = tid; idx < tot; idx += 256) {
      int q  = idx >> 5;
      int a  = q < p0 ? q : hi_start + (q - p0);
      int c4 = idx & 31;
      *(float4*)(outb + (size_t)(par + 2 * a) * COUT + c4 * 4) = z;
    }
  }

  // ---- epilogue: elu(conv + offset), hex-masked; C/D: col=lane&15, row=quad*4+reg ----
  const float off0 = offs[n0 + l15];
  const float off1 = offs[n0 + 16 + l15];
  #pragma unroll
  for (int mf = 0; mf < 5; ++mf) {
    if (mf < nf) {
      #pragma unroll
      for (int r = 0; r < 4; ++r) {
        int a  = (f0 + mf) * 16 + quad * 4 + r;
        int oj = par + 2 * a;
        if (oj <= OW - 1) {
          int adj = oj - 64; adj = adj < 0 ? -adj : adj;
          bool valid = adj <= lim;
          float v0 = acc[mf][0][r] + off0;
          float v1 = acc[mf][1][r] + off1;
          // elu: exp(v)-1 instead of expm1 — abs err ~1e-7, ~8x fewer VALU insts
          float e0 = v0 > 0.f ? v0 : (__expf(v0) - 1.0f);
          float e1 = v1 > 0.f ? v1 : (__expf(v1) - 1.0f);
          outb[(size_t)oj * COUT + n0 + l15]      = valid ? e0 : 0.f;
          outb[(size_t)oj * COUT + n0 + 16 + l15] = valid ? e1 : 0.f;
        }
      }
    }
  }
}

extern "C" void kernel_launch(void* const* d_in, const int* in_sizes, int n_in,
                              void* d_out, int out_size, void* d_ws, size_t ws_size,
                              hipStream_t stream) {
  const float* x   = (const float*)d_in[0];
  const float* sw  = (const float*)d_in[1];
  const float* off = (const float*)d_in[2];
  float* out = (float*)d_out;

  unsigned short* wtb = (unsigned short*)d_ws;     // 311 KB
  repack_w<<<NW / 256, 256, 0, stream>>>(sw, wtb);
  conv_hex_mfma<<<NBLK, 256, 0, stream>>>(x, wtb, off, out);
}